// Round 3
// baseline (908.422 us; speedup 1.0000x reference)
//
#include <hip/hip_runtime.h>

// Trilinear sparse-voxel upsampling, SCALE=2, R=128, C=32.
// fine = 2*c + o (o in {0,1}^3) => per-axis neighbors {c-1+o (w=0.25+0.5o), c+o (w=0.75-0.5o)}.
//
// Wave-per-coarse-voxel, PERSISTENT waves with a 1-deep software pipeline:
//   iteration k: stage feat(k) [loads issued at k-1] -> issue feat(k+1) loads
//                -> issue table probe(k+2) -> compute+store voxel k from LDS.
// Both random-load latencies (table, feat) hide under compute/store of the
// previous voxel. Processing order == input order, so the dominant 410 MB
// output stream stays sequential (round-2 lesson: never randomize the writes).

#define R 128
#define TABLE_ELEMS (R * R * R)

typedef float f32x4 __attribute__((ext_vector_type(4)));

__global__ void build_table_kernel(const int* __restrict__ coarse,
                                   int* __restrict__ table, int n) {
    int i = blockIdx.x * blockDim.x + threadIdx.x;
    if (i >= n) return;
    int x = coarse[i * 3 + 0];
    int y = coarse[i * 3 + 1];
    int z = coarse[i * 3 + 2];
    // numpy last-write-wins with increasing values == max row index
    atomicMax(&table[(x * R + y) * R + z], i);
}

__global__ void __launch_bounds__(256, 7)
upsample_kernel(const f32x4* __restrict__ feat4,   // [n_in, 8] f32x4 == [n_in,32] f32
                const int* __restrict__ coarse,    // [n_in, 3]
                const int* __restrict__ table,     // [128^3]
                f32x4* __restrict__ out4,          // [8*n_in, 8] f32x4
                int n_in, int nw) {                // nw = total waves launched
    __shared__ f32x4 sm[4][27 * 8];                // 13824 B: one buffer per wave

    int wib  = threadIdx.x >> 6;
    int lane = threadIdx.x & 63;
    int wid  = __builtin_amdgcn_readfirstlane(blockIdx.x * 4 + wib);
    f32x4* smw = sm[wib];

    int g    = lane >> 3;                          // row-slot / child id
    int part = lane & 7;                           // which f32x4 of the 32-ch row

    // probe-lane decode (lanes 0..26 each own one of the 27 neighbors)
    int dx   = lane / 9;
    int prem = lane - dx * 9;
    int dy   = prem / 3;
    int dz   = prem - dy * 3;
    bool isprobe = lane < 27;

    // child decode + exact trilinear weights
    int ox = (g >> 2) & 1, oy = (g >> 1) & 1, oz = g & 1;
    float wx0 = 0.25f + 0.5f * (float)ox, wx1 = 0.75f - 0.5f * (float)ox;
    float wy0 = 0.25f + 0.5f * (float)oy, wy1 = 0.75f - 0.5f * (float)oy;
    float wz0 = 0.25f + 0.5f * (float)oz, wz1 = 0.75f - 0.5f * (float)oz;

    // one 27-neighborhood hash probe; guarded for tail / OOB
    auto probe = [&](int vi) -> int {
        int idx = -1;
        if (vi < n_in && isprobe) {
            int cx = coarse[vi * 3 + 0];
            int cy = coarse[vi * 3 + 1];
            int cz = coarse[vi * 3 + 2];
            int x = cx + dx - 1, y = cy + dy - 1, z = cz + dz - 1;
            if ((unsigned)x < (unsigned)R && (unsigned)y < (unsigned)R &&
                (unsigned)z < (unsigned)R)
                idx = table[(x * R + y) * R + z];
        }
        return idx;
    };

    // ---- prologue: fill the pipeline for voxel wid and wid+nw ----
    int vi = wid;
    int m_cur = probe(vi);                         // table probe, voxel k=0
    unsigned long long vmask = __ballot(m_cur >= 0);
    int i0 = __shfl(m_cur, g);                     // row indices for slots g,8+g,16+g,24+g
    int i1 = __shfl(m_cur, 8 + g);
    int i2 = __shfl(m_cur, 16 + g);
    int i3 = __shfl(m_cur, 24 + g);                // slots 27..31 always -1
    f32x4 f0, f1, f2, f3;
    if (i0 >= 0) f0 = feat4[(size_t)i0 * 8 + part];
    if (i1 >= 0) f1 = feat4[(size_t)i1 * 8 + part];
    if (i2 >= 0) f2 = feat4[(size_t)i2 * 8 + part];
    if (i3 >= 0) f3 = feat4[(size_t)i3 * 8 + part];
    int m_nxt = probe(vi + nw);                    // table probe, voxel k=1

    while (vi < n_in) {
        // ---- stage current feat rows into this wave's LDS buffer ----
        // (single buffer is safe: DS ops of one wave retire in order, and the
        //  previous iteration's ds_reads precede these ds_writes in program order)
        if (i0 >= 0) smw[(g)      * 8 + part] = f0;
        if (i1 >= 0) smw[(8 + g)  * 8 + part] = f1;
        if (i2 >= 0) smw[(16 + g) * 8 + part] = f2;
        if (i3 >= 0) smw[(24 + g) * 8 + part] = f3;

        // ---- next voxel: redistribute probe results, issue feat loads ----
        unsigned long long vmask_n = __ballot(m_nxt >= 0);
        int n0 = __shfl(m_nxt, g);
        int n1 = __shfl(m_nxt, 8 + g);
        int n2 = __shfl(m_nxt, 16 + g);
        int n3 = __shfl(m_nxt, 24 + g);
        f32x4 nf0, nf1, nf2, nf3;
        if (n0 >= 0) nf0 = feat4[(size_t)n0 * 8 + part];
        if (n1 >= 0) nf1 = feat4[(size_t)n1 * 8 + part];
        if (n2 >= 0) nf2 = feat4[(size_t)n2 * 8 + part];
        if (n3 >= 0) nf3 = feat4[(size_t)n3 * 8 + part];

        // ---- issue next-next table probe (hides under compute below) ----
        int m_nn = probe(vi + 2 * nw);

        // ---- compute current voxel's 8 children from LDS ----
        asm volatile("s_waitcnt lgkmcnt(0)" ::: "memory");
        __builtin_amdgcn_sched_barrier(0);
        f32x4 acc = (f32x4)(0.f);
#pragma unroll
        for (int k = 0; k < 8; ++k) {
            int kx = (k >> 2) & 1, ky = (k >> 1) & 1, kz = k & 1;
            int nb = (ox + kx) * 9 + (oy + ky) * 3 + (oz + kz);
            if ((vmask >> nb) & 1ull) {
                float w = (kx ? wx1 : wx0) * (ky ? wy1 : wy0) * (kz ? wz1 : wz0);
                acc += w * smw[nb * 8 + part];
            }
        }
        // out row m = vi*8 + child; element m*8 + part == vi*64 + lane
        // (1 KB/wave; concurrent waves cover a contiguous ~7 MB window)
        __builtin_nontemporal_store(acc, &out4[(size_t)vi * 64 + lane]);

        // ---- rotate pipeline registers ----
        vi += nw;
        vmask = vmask_n;
        i0 = n0; i1 = n1; i2 = n2; i3 = n3;
        f0 = nf0; f1 = nf1; f2 = nf2; f3 = nf3;
        m_nxt = m_nn;
    }
}

extern "C" void kernel_launch(void* const* d_in, const int* in_sizes, int n_in_arrs,
                              void* d_out, int out_size, void* d_ws, size_t ws_size,
                              hipStream_t stream) {
    const float* feat = (const float*)d_in[0];
    const int* coarse = (const int*)d_in[1];
    // d_in[2] (fine_coords) is derivable from coarse_coords -- not read.

    int n_in = in_sizes[1] / 3;            // 400000
    int* table = (int*)d_ws;               // 8 MiB scratch

    hipMemsetAsync(table, 0xFF, (size_t)TABLE_ELEMS * sizeof(int), stream);

    build_table_kernel<<<(n_in + 255) / 256, 256, 0, stream>>>(coarse, table, n_in);

    // persistent grid: 7 blocks/CU * 256 CUs (matches __launch_bounds__(256,7))
    int nblocks = 1792;
    int max_needed = (n_in + 3) / 4;       // one wave per voxel would need this
    if (nblocks > max_needed) nblocks = max_needed;
    int nw = nblocks * 4;                  // total waves; each strides by nw

    upsample_kernel<<<nblocks, 256, 0, stream>>>(
        (const f32x4*)feat, coarse, table, (f32x4*)d_out, n_in, nw);
}

// Round 4
// 611.146 us; speedup vs baseline: 1.4864x; 1.4864x over previous
//
#include <hip/hip_runtime.h>

// Trilinear sparse-voxel upsampling, SCALE=2, R=128, C=32.
// fine = 2*c + o (o in {0,1}^3) => per-axis neighbors {c-1+o (w=0.25+0.5o), c+o (w=0.75-0.5o)}.
//
// Round-1 structure (best): wave-per-coarse-voxel, short-lived blocks in input
// order (HW dispatch order = sliding cache window; round-3 lesson: persistent
// grids forfeit this). New in round 4: 256 KB occupancy BITMAP pre-filter,
// L2-resident, so the 8 MB table is only probed for the ~6/27 occupied
// neighbors (exec-masked lanes issue no requests) -> ~half the table line
// traffic and less L2/L3 pollution competing with feat rows.
//   Phase 1: lanes 0-26 probe bitmap, then table only if occupied (ballot mask)
//   Phase 2: cooperative staging of valid feat rows into LDS
//   Phase 3: each lane (child, part) combines its 8 corners from LDS.

#define R 128
#define TABLE_ELEMS (R * R * R)
#define BITMAP_WORDS (TABLE_ELEMS / 32)    // 65536 words = 256 KB

typedef float f32x4 __attribute__((ext_vector_type(4)));

__global__ void build_table_kernel(const int* __restrict__ coarse,
                                   int* __restrict__ table,
                                   unsigned* __restrict__ bitmap, int n) {
    int i = blockIdx.x * blockDim.x + threadIdx.x;
    if (i >= n) return;
    int x = coarse[i * 3 + 0];
    int y = coarse[i * 3 + 1];
    int z = coarse[i * 3 + 2];
    int lin = (x * R + y) * R + z;
    // numpy last-write-wins with increasing values == max row index
    atomicMax(&table[lin], i);
    atomicOr(&bitmap[lin >> 5], 1u << (lin & 31));
}

__global__ void __launch_bounds__(256)
upsample_kernel(const f32x4* __restrict__ feat4,    // [n_in, 8] f32x4 == [n_in,32] f32
                const int* __restrict__ coarse,     // [n_in, 3]
                const int* __restrict__ table,      // [128^3] row index or -1
                const unsigned* __restrict__ bitmap,// [128^3 / 32] occupancy bits
                f32x4* __restrict__ out4,           // [8*n_in, 8] f32x4
                int n_in) {
    __shared__ f32x4 sm[4][27 * 8];                 // 13824 B: 27 neighbor rows per wave

    int wib  = threadIdx.x >> 6;                    // wave within block
    int lane = threadIdx.x & 63;
    int vi   = blockIdx.x * 4 + wib;                // one coarse voxel per wave
    vi = __builtin_amdgcn_readfirstlane(vi);        // force SGPR (wave-uniform)
    if (vi >= n_in) return;

    int cx = coarse[vi * 3 + 0];
    int cy = coarse[vi * 3 + 1];
    int cz = coarse[vi * 3 + 2];

    // ---- Phase 1: 27-neighborhood lookup, one neighbor per lane ----
    // bitmap probe first (256 KB, L2-hot); dense table only for occupied cells.
    int myidx = -1;
    if (lane < 27) {
        int dx  = lane / 9;
        int rem = lane - dx * 9;
        int dy  = rem / 3;
        int dz  = rem - dy * 3;
        int x = cx + dx - 1, y = cy + dy - 1, z = cz + dz - 1;
        if ((unsigned)x < (unsigned)R && (unsigned)y < (unsigned)R &&
            (unsigned)z < (unsigned)R) {
            int lin = (x * R + y) * R + z;
            if ((bitmap[lin >> 5] >> (lin & 31)) & 1u)
                myidx = table[lin];                 // only ~6/27 lanes reach here
        }
    }
    unsigned long long vmask = __ballot(myidx >= 0);    // wave-uniform validity

    // ---- Phase 2: stage valid neighbor rows into LDS ----
    int g = lane >> 3;                              // row-slot / child id
    int part = lane & 7;                            // which f32x4 of the 32-ch row
    f32x4* smw = sm[wib];
#pragma unroll
    for (int r = 0; r < 4; ++r) {
        int nb  = r * 8 + g;                        // 0..31; 27..31 are always invalid
        int idx = __shfl(myidx, nb);                // lanes >=27 hold -1
        if (idx >= 0)
            smw[nb * 8 + part] = feat4[(size_t)idx * 8 + part];
    }
    // wave-local producer->consumer: drain our own ds_writes before reading
    asm volatile("s_waitcnt lgkmcnt(0)" ::: "memory");
    __builtin_amdgcn_sched_barrier(0);

    // ---- Phase 3: child (g) x part: combine 8 corners from LDS ----
    int ox = (g >> 2) & 1, oy = (g >> 1) & 1, oz = g & 1;
    float wx0 = 0.25f + 0.5f * (float)ox, wx1 = 0.75f - 0.5f * (float)ox;
    float wy0 = 0.25f + 0.5f * (float)oy, wy1 = 0.75f - 0.5f * (float)oy;
    float wz0 = 0.25f + 0.5f * (float)oz, wz1 = 0.75f - 0.5f * (float)oz;

    f32x4 acc = (f32x4)(0.f);
#pragma unroll
    for (int k = 0; k < 8; ++k) {
        int kx = (k >> 2) & 1, ky = (k >> 1) & 1, kz = k & 1;
        int nb = (ox + kx) * 9 + (oy + ky) * 3 + (oz + kz);
        if ((vmask >> nb) & 1ull) {
            float w = (kx ? wx1 : wx0) * (ky ? wy1 : wy0) * (kz ? wz1 : wz0);
            f32x4 f = smw[nb * 8 + part];
            acc += w * f;
        }
    }

    // out row m = vi*8 + child; element m*8 + part == vi*64 + lane
    // (1 KB contiguous NT burst per wave, sequential across waves)
    __builtin_nontemporal_store(acc, &out4[(size_t)vi * 64 + lane]);
}

extern "C" void kernel_launch(void* const* d_in, const int* in_sizes, int n_in_arrs,
                              void* d_out, int out_size, void* d_ws, size_t ws_size,
                              hipStream_t stream) {
    const float* feat = (const float*)d_in[0];
    const int* coarse = (const int*)d_in[1];
    // d_in[2] (fine_coords) is derivable from coarse_coords -- not read.

    int n_in = in_sizes[1] / 3;            // 400000

    // workspace layout: table (8 MiB) | bitmap (256 KB)
    int* table       = (int*)d_ws;
    unsigned* bitmap = (unsigned*)(table + TABLE_ELEMS);

    hipMemsetAsync(table, 0xFF, (size_t)TABLE_ELEMS * sizeof(int), stream);
    hipMemsetAsync(bitmap, 0x00, (size_t)BITMAP_WORDS * sizeof(unsigned), stream);

    build_table_kernel<<<(n_in + 255) / 256, 256, 0, stream>>>(coarse, table, bitmap, n_in);

    int nblocks = (n_in + 3) / 4;          // one wave (64 threads) per coarse voxel
    upsample_kernel<<<nblocks, 256, 0, stream>>>(
        (const f32x4*)feat, coarse, table, bitmap, (f32x4*)d_out, n_in);
}

// Round 5
// 567.512 us; speedup vs baseline: 1.6007x; 1.0769x over previous
//
#include <hip/hip_runtime.h>

// Trilinear sparse-voxel upsampling, SCALE=2, R=128, C=32.
// fine = 2*c + o (o in {0,1}^3) => per-axis neighbors {c-1+o (w=0.25+0.5o), c+o (w=0.75-0.5o)}.
//
// Round-1 structure (best so far) + 2 voxels per wave for doubled MLP:
//   - lanes 0-26 probe voxel A's 27 neighbors, lanes 32-58 voxel B's
//     (one load instruction, one ballot -> both validity masks)
//   - 8 staging rounds (4 per voxel) issue global_load_lds direct-to-LDS,
//     all in ONE latency window, then a single vmcnt(0)
//   - compute+store A, then B; stores stay sequential (viB = viA+1)
// Short-lived blocks in input order (round-3 lesson: HW dispatch windowing IS
// the cache policy). No bitmap pre-filter (round-4 lesson: never deepen the
// serial probe chain). Writes nontemporal + input-ordered (round-2 lesson).

#define R 128
#define TABLE_ELEMS (R * R * R)

typedef float f32x4 __attribute__((ext_vector_type(4)));

__global__ void build_table_kernel(const int* __restrict__ coarse,
                                   int* __restrict__ table, int n) {
    int i = blockIdx.x * blockDim.x + threadIdx.x;
    if (i >= n) return;
    int x = coarse[i * 3 + 0];
    int y = coarse[i * 3 + 1];
    int z = coarse[i * 3 + 2];
    // numpy last-write-wins with increasing values == max row index
    atomicMax(&table[(x * R + y) * R + z], i);
}

// direct global->LDS, 16 B/lane; LDS dest is wave-uniform base + lane*16
__device__ __forceinline__ void gload_lds16(const f32x4* g, f32x4* l) {
    __builtin_amdgcn_global_load_lds(
        (const __attribute__((address_space(1))) void*)g,
        (__attribute__((address_space(3))) void*)l, 16, 0, 0);
}

__global__ void __launch_bounds__(256)
upsample_kernel(const f32x4* __restrict__ feat4,   // [n_in, 8] f32x4 == [n_in,32] f32
                const int* __restrict__ coarse,    // [n_in, 3]
                const int* __restrict__ table,     // [128^3] row index or -1
                f32x4* __restrict__ out4,          // [8*n_in, 8] f32x4
                int n_in) {
    // per wave: 2 voxels x 32 slots x 8 parts (slots 27-31 are never-read pads
    // so each staging round's LDS window is exactly base + lane*16)
    __shared__ f32x4 sm[4][2][256];                // 32 KiB per block

    int wib  = threadIdx.x >> 6;                   // wave within block
    int lane = threadIdx.x & 63;
    int half = lane >> 5;                          // 0: voxel A probes, 1: voxel B
    int pl   = lane & 31;                          // probe slot within half

    int viA = __builtin_amdgcn_readfirstlane(blockIdx.x * 8 + wib * 2);
    if (viA >= n_in) return;
    int viB = viA + 1;

    // ---- Phase 1: both voxels' 27-neighborhoods in ONE probe instruction ----
    int vi_p = half ? viB : viA;
    int myidx = -1;
    if (pl < 27 && vi_p < n_in) {
        int cx = coarse[vi_p * 3 + 0];
        int cy = coarse[vi_p * 3 + 1];
        int cz = coarse[vi_p * 3 + 2];
        int dx  = pl / 9;
        int rem = pl - dx * 9;
        int dy  = rem / 3;
        int dz  = rem - dy * 3;
        int x = cx + dx - 1, y = cy + dy - 1, z = cz + dz - 1;
        if ((unsigned)x < (unsigned)R && (unsigned)y < (unsigned)R &&
            (unsigned)z < (unsigned)R)
            myidx = table[(x * R + y) * R + z];
    }
    unsigned long long vmask = __ballot(myidx >= 0);
    unsigned maskA = (unsigned)(vmask & 0x7FFFFFFull);
    unsigned maskB = (unsigned)((vmask >> 32) & 0x7FFFFFFull);

    // ---- Phase 2: stage both voxels' feat rows direct-to-LDS, one window ----
    int g    = lane >> 3;                          // row-slot / child id
    int part = lane & 7;                           // which f32x4 of the 32-ch row
    f32x4* smA = &sm[wib][0][0];
    f32x4* smB = &sm[wib][1][0];
#pragma unroll
    for (int r = 0; r < 4; ++r) {                  // voxel A, slots r*8+g
        int idx = __shfl(myidx, r * 8 + g);        // lanes 27-31 hold -1
        if (idx >= 0)
            gload_lds16(&feat4[(size_t)idx * 8 + part], smA + r * 64);
    }
#pragma unroll
    for (int r = 0; r < 4; ++r) {                  // voxel B, slots from lanes 32+
        int idx = __shfl(myidx, 32 + r * 8 + g);   // lanes 59-63 hold -1
        if (idx >= 0)
            gload_lds16(&feat4[(size_t)idx * 8 + part], smB + r * 64);
    }
    asm volatile("s_waitcnt vmcnt(0)" ::: "memory");
    __builtin_amdgcn_sched_barrier(0);             // rule 18: pin ds_reads after wait

    // ---- Phase 3: child (g) x part: combine 8 corners from LDS ----
    int ox = (g >> 2) & 1, oy = (g >> 1) & 1, oz = g & 1;
    float wx0 = 0.25f + 0.5f * (float)ox, wx1 = 0.75f - 0.5f * (float)ox;
    float wy0 = 0.25f + 0.5f * (float)oy, wy1 = 0.75f - 0.5f * (float)oy;
    float wz0 = 0.25f + 0.5f * (float)oz, wz1 = 0.75f - 0.5f * (float)oz;

    f32x4 accA = (f32x4)(0.f);
    f32x4 accB = (f32x4)(0.f);
#pragma unroll
    for (int k = 0; k < 8; ++k) {
        int kx = (k >> 2) & 1, ky = (k >> 1) & 1, kz = k & 1;
        int nb = (ox + kx) * 9 + (oy + ky) * 3 + (oz + kz);
        float w = (kx ? wx1 : wx0) * (ky ? wy1 : wy0) * (kz ? wz1 : wz0);
        if ((maskA >> nb) & 1u) accA += w * smA[nb * 8 + part];
        if ((maskB >> nb) & 1u) accB += w * smB[nb * 8 + part];
    }

    // out row m = vi*8 + child; element m*8 + part == vi*64 + lane
    // (2 KB of sequential NT stores per wave)
    __builtin_nontemporal_store(accA, &out4[(size_t)viA * 64 + lane]);
    if (viB < n_in)
        __builtin_nontemporal_store(accB, &out4[(size_t)viB * 64 + lane]);
}

extern "C" void kernel_launch(void* const* d_in, const int* in_sizes, int n_in_arrs,
                              void* d_out, int out_size, void* d_ws, size_t ws_size,
                              hipStream_t stream) {
    const float* feat = (const float*)d_in[0];
    const int* coarse = (const int*)d_in[1];
    // d_in[2] (fine_coords) is derivable from coarse_coords -- not read.

    int n_in = in_sizes[1] / 3;            // 400000
    int* table = (int*)d_ws;               // 8 MiB scratch

    hipMemsetAsync(table, 0xFF, (size_t)TABLE_ELEMS * sizeof(int), stream);

    build_table_kernel<<<(n_in + 255) / 256, 256, 0, stream>>>(coarse, table, n_in);

    int nblocks = (n_in + 7) / 8;          // 2 voxels per wave, 4 waves per block
    upsample_kernel<<<nblocks, 256, 0, stream>>>(
        (const f32x4*)feat, coarse, table, (f32x4*)d_out, n_in);
}